// Round 1
// baseline (189.886 us; speedup 1.0000x reference)
//
#include <hip/hip_runtime.h>
#include <hip/hip_bf16.h>

#define NN_ 8192
#define DD_ 128
#define NSPLIT 4
#define JSPLIT (NN_ / NSPLIT)  // 2048

typedef short bf16x8 __attribute__((ext_vector_type(8)));
typedef float f32x4 __attribute__((ext_vector_type(4)));

union U4 { uint4 u; bf16x8 h; };

__device__ __forceinline__ unsigned short f2bf(float f) {
    unsigned int u = __float_as_uint(f);
    unsigned int r = (u + 0x7FFFu + ((u >> 16) & 1u)) >> 16;  // RNE
    return (unsigned short)r;
}

// ---------------- kernel 1: L2-normalize rows -> bf16, class histogram ----------
__global__ __launch_bounds__(64) void k_norm(const float* __restrict__ x,
                                             const int* __restrict__ labels,
                                             unsigned short* __restrict__ ebf,
                                             int* __restrict__ hist) {
    int row = blockIdx.x;
    int t = threadIdx.x;
    float2 v = ((const float2*)(x + (size_t)row * DD_))[t];
    float ss = v.x * v.x + v.y * v.y;
#pragma unroll
    for (int m = 1; m < 64; m <<= 1) ss += __shfl_xor(ss, m);
    float inv = 1.0f / fmaxf(sqrtf(ss), 1e-12f);
    unsigned short hx = f2bf(v.x * inv);
    unsigned short hy = f2bf(v.y * inv);
    unsigned int packed = (unsigned int)hx | ((unsigned int)hy << 16);
    ((unsigned int*)ebf)[row * (DD_ / 2) + t] = packed;
    if (t == 0) atomicAdd(&hist[labels[row]], 1);
}

// ---------------- kernel 2: main sim + masked LSE pass --------------------------
// grid (NSPLIT, NN_/128), block 512 (8 waves). Wave w owns rows
// blockIdx.y*128 + w*16 .. +15 ; scans j in [jsplit*2048, +2048) in steps of 16.
__global__ __launch_bounds__(512) void k_main(const unsigned short* __restrict__ ebf,
                                              const int* __restrict__ labels,
                                              float* __restrict__ states) {
    const int lane = threadIdx.x & 63;
    const int wave = threadIdx.x >> 6;
    const int quad = lane >> 4;
    const int lcol = lane & 15;
    const int rowbase = blockIdx.y * 128 + wave * 16;
    const int jsplit = blockIdx.x;
    const int j0 = jsplit * JSPLIT, j1 = j0 + JSPLIT;

    const uint4* eb4 = (const uint4*)ebf;  // 16B units; row stride = 16 units

    // A fragments: resident for the whole kernel. A[m=lane&15][k=quad*8+j]
    U4 afr[4];
    int arow = rowbase + lcol;
#pragma unroll
    for (int kc = 0; kc < 4; kc++) afr[kc].u = eb4[arow * 16 + kc * 4 + quad];

    int il[4];
#pragma unroll
    for (int r = 0; r < 4; r++) il[r] = labels[rowbase + quad * 4 + r];

    float S_an[4] = {0.f, 0.f, 0.f, 0.f};
    float m_p[4] = {-1e30f, -1e30f, -1e30f, -1e30f};
    float s_p[4] = {0.f, 0.f, 0.f, 0.f};

    U4 bfr[4];
#pragma unroll
    for (int kc = 0; kc < 4; kc++) bfr[kc].u = eb4[(j0 + lcol) * 16 + kc * 4 + quad];

    for (int jt = j0; jt < j1; jt += 16) {
        // prefetch next B tile (always-valid address)
        int jn = (jt + 16 < j1) ? (jt + 16) : j0;
        U4 bnx[4];
#pragma unroll
        for (int kc = 0; kc < 4; kc++) bnx[kc].u = eb4[(jn + lcol) * 16 + kc * 4 + quad];

        f32x4 acc = {0.f, 0.f, 0.f, 0.f};
#pragma unroll
        for (int kc = 0; kc < 4; kc++)
            acc = __builtin_amdgcn_mfma_f32_16x16x32_bf16(afr[kc].h, bfr[kc].h, acc, 0, 0, 0);

        int j = jt + lcol;
        int jl = labels[j];
#pragma unroll
        for (int r = 0; r < 4; r++) {
            float s = acc[r];
            int i = rowbase + quad * 4 + r;
            bool same = (jl == il[r]);
            // negatives: an_term = 80*relu(s+0.4)*(s-0.4), fixed shift 67.2 (max)
            float a = fmaxf(s + 0.4f, 0.0f) * 80.0f;
            float t = fmaf(a, s - 0.4f, -67.2f);
            float e = __expf(t);
            S_an[r] += same ? 0.0f : e;
            // positives (rare): ap_term = -80*relu(1.4-s)*(s-0.6), online LSE
            if (same && j != i) {
                float al = fmaxf(1.4f - s, 0.0f) * -80.0f;
                float tp = al * (s - 0.6f);
                float mn = fmaxf(m_p[r], tp);
                s_p[r] = s_p[r] * __expf(m_p[r] - mn) + __expf(tp - mn);
                m_p[r] = mn;
            }
        }
#pragma unroll
        for (int kc = 0; kc < 4; kc++) bfr[kc] = bnx[kc];
    }

    // merge the 16 column-stripes of each row (lanes sharing quad)
#pragma unroll
    for (int r = 0; r < 4; r++) {
#pragma unroll
        for (int m = 1; m < 16; m <<= 1) {
            S_an[r] += __shfl_xor(S_an[r], m);
            float m2 = __shfl_xor(m_p[r], m);
            float s2 = __shfl_xor(s_p[r], m);
            float mn = fmaxf(m_p[r], m2);
            s_p[r] = s_p[r] * __expf(m_p[r] - mn) + s2 * __expf(m2 - mn);
            m_p[r] = mn;
        }
    }
    if (lcol == 0) {
#pragma unroll
        for (int r = 0; r < 4; r++) {
            int i = rowbase + quad * 4 + r;
            float* st = states + ((size_t)i * NSPLIT + jsplit) * 3;
            st[0] = m_p[r];
            st[1] = s_p[r];
            st[2] = S_an[r];
        }
    }
}

// ---------------- kernel 3: merge splits, per-row loss, block reduce ------------
__global__ __launch_bounds__(256) void k_fin(const float* __restrict__ states,
                                             const int* __restrict__ labels,
                                             const int* __restrict__ hist,
                                             float* __restrict__ accum) {
    int i = blockIdx.x * 256 + threadIdx.x;
    int cnt = hist[labels[i]];
    int np = cnt - 1, nn = NN_ - cnt;
    float m_p = -1e30f, s_p = 0.f, S_an = 0.f;
#pragma unroll
    for (int k = 0; k < NSPLIT; k++) {
        const float* st = states + ((size_t)i * NSPLIT + k) * 3;
        float m2 = st[0], s2 = st[1];
        S_an += st[2];
        float mn = fmaxf(m_p, m2);
        s_p = s_p * __expf(m_p - mn) + s2 * __expf(m2 - mn);
        m_p = mn;
    }
    float loss = 0.0f, v = 0.0f;
    if (np > 0 && nn > 0 && s_p > 0.f && S_an > 0.f) {
        float lse_p = m_p + __logf(s_p);
        float lse_n = 67.2f + __logf(S_an);
        float z = lse_p + lse_n + __logf((float)np) + __logf((float)nn);
        loss = fmaxf(z, 0.0f) + log1pf(__expf(-fabsf(z)));  // softplus, stable
        v = 1.0f;
    }
#pragma unroll
    for (int m = 1; m < 64; m <<= 1) {
        loss += __shfl_xor(loss, m);
        v += __shfl_xor(v, m);
    }
    if ((threadIdx.x & 63) == 0) {
        atomicAdd(&accum[0], loss);
        atomicAdd(&accum[1], v);
    }
}

__global__ void k_div(const float* __restrict__ accum, float* __restrict__ out) {
    if (threadIdx.x == 0) out[0] = accum[0] / fmaxf(accum[1], 1.0f);
}

// ---------------- launch --------------------------------------------------------
extern "C" void kernel_launch(void* const* d_in, const int* in_sizes, int n_in,
                              void* d_out, int out_size, void* d_ws, size_t ws_size,
                              hipStream_t stream) {
    const float* embeds = (const float*)d_in[0];
    const int* labels = (const int*)d_in[1];
    float* out = (float*)d_out;

    char* ws = (char*)d_ws;
    unsigned short* ebf = (unsigned short*)ws;              // 8192*128*2 = 2097152 B
    float* states = (float*)(ws + 2097152);                 // 8192*4*3*4 = 393216 B
    int* hist = (int*)(ws + 2097152 + 393216);              // 2048 B
    float* accum = (float*)(ws + 2097152 + 393216 + 2048);  // 8 B

    hipMemsetAsync(hist, 0, 2048 + 8, stream);  // zero hist + accum (contiguous)

    k_norm<<<NN_, 64, 0, stream>>>(embeds, labels, ebf, hist);
    k_main<<<dim3(NSPLIT, NN_ / 128), 512, 0, stream>>>(ebf, labels, states);
    k_fin<<<NN_ / 256, 256, 0, stream>>>(states, labels, hist, accum);
    k_div<<<1, 64, 0, stream>>>(accum, out);
}